// Round 3
// baseline (538.910 us; speedup 1.0000x reference)
//
#include <hip/hip_runtime.h>
#include <hip/hip_bf16.h>
#include <stdint.h>

// ConvDecoderLayer: B=8, T=S=2048, D=512, K=3
// out = (LN2(h + (attn@v)@Wo^T + bo), attn), h = LN1(GLU(causal_conv(x)) + x)

typedef unsigned short ushortT;
typedef __bf16 bf16x8 __attribute__((ext_vector_type(8)));
typedef float floatx4 __attribute__((ext_vector_type(4)));
typedef unsigned short ushort4v __attribute__((ext_vector_type(4)));
typedef unsigned short ushort8 __attribute__((ext_vector_type(8)));

__device__ __forceinline__ ushortT f2bf(float f) {
  unsigned u = __builtin_bit_cast(unsigned, f);
  u += 0x7FFFu + ((u >> 16) & 1u);   // RNE
  return (ushortT)(u >> 16);
}
__device__ __forceinline__ float bf2f(ushortT u) {
  return __builtin_bit_cast(float, (unsigned)u << 16);
}

__device__ __forceinline__ void gload_lds16(const void* g, void* l) {
  __builtin_amdgcn_global_load_lds(
      (const __attribute__((address_space(1))) void*)g,
      (__attribute__((address_space(3))) void*)l, 16, 0, 0);
}

// ---------------- conversion kernels ----------------
__global__ __launch_bounds__(256)
void k_f32_to_bf16v(const float* __restrict__ src, ushortT* __restrict__ dst, long n4) {
  long i = (long)blockIdx.x * 256 + threadIdx.x;
  if (i >= n4) return;
  floatx4 v = *(const floatx4*)&src[i * 4];
  ushort4v o;
#pragma unroll
  for (int j = 0; j < 4; j++) o[j] = f2bf(v[j]);
  *(ushort4v*)&dst[i * 4] = o;
}

// four 512x512 weights -> bf16, one launch
__global__ __launch_bounds__(256)
void k_w4(const float* __restrict__ w0, const float* __restrict__ w1,
          const float* __restrict__ w2, const float* __restrict__ w3,
          ushortT* __restrict__ dst) {
  long i = (long)blockIdx.x * 256 + threadIdx.x;   // float4 groups, 4*65536 total
  int m = (int)(i >> 16);
  long within = (i & 65535) * 4;
  const float* s = (m == 0) ? w0 : (m == 1) ? w1 : (m == 2) ? w2 : w3;
  floatx4 v = *(const floatx4*)&s[within];
  ushort4v o;
#pragma unroll
  for (int j = 0; j < 4; j++) o[j] = f2bf(v[j]);
  *(ushort4v*)&dst[(long)m * 262144 + within] = o;
}

// x [8,2048,512] f32 -> xpad [8,2050,512] bf16 with 2 leading zero rows per batch
__global__ __launch_bounds__(128)
void k_xpad(const float* __restrict__ x, ushortT* __restrict__ xp) {
  int row = blockIdx.x;                 // 8*2050
  int b = row / 2050, tp = row % 2050;
  int c = threadIdx.x * 4;
  ushort4v o = {0, 0, 0, 0};
  if (tp >= 2) {
    floatx4 v = *(const floatx4*)&x[((long)(b * 2048 + tp - 2)) * 512 + c];
#pragma unroll
    for (int j = 0; j < 4; j++) o[j] = f2bf(v[j]);
  }
  *(ushort4v*)&xp[(long)row * 512 + c] = o;
}

// conv_w [1024][512][3] -> interleaved B^T form Wc'[n][kk], kk = tap*512+i
__global__ __launch_bounds__(256)
void k_convw(const float* __restrict__ w, ushortT* __restrict__ dst) {
  long idx = (long)blockIdx.x * 256 + threadIdx.x;
  if (idx >= 1024L * 1536) return;
  int n = (int)(idx / 1536), kk = (int)(idx % 1536);
  int tap = kk >> 9, i = kk & 511;
  int o = ((n >> 4) & 1) * 512 + (n >> 5) * 16 + (n & 15);
  dst[idx] = f2bf(w[(o * 512 + i) * 3 + tap]);
}

// ---------------- 256x256 phased counted-vmcnt GEMM ----------------
// 8 waves (2M x 4N), BK=64, 128 KiB LDS. T2 swizzle + T3/T4 counted vmcnt + T5.
// Per tile: 3 barriers. After cluster-0's barrier, all B reads and A rows
// {0-63,128-191} are consumed -> 6 of 8 prefetch loads for t+2 issue
// concurrently with cluster-1 (disjoint LDS regions); last 2 issue post-tile.
template<int CONV_A, int GLU, int BIAS, int WBF16, int DUALZ, int SWAP>
__global__ __launch_bounds__(512)
void k_gemm256(const ushortT* __restrict__ A, const ushortT* __restrict__ A2, int lda, long aBatch,
               const ushortT* __restrict__ Bm, const ushortT* __restrict__ Bm2, int ldb, long bBatch,
               const float* __restrict__ bias, const float* __restrict__ bias2,
               const float* __restrict__ xres,
               float* __restrict__ Cf, ushortT* __restrict__ Cb, ushortT* __restrict__ Cb2,
               long cBatch, int ldc, int Kdim, float scale)
{
  __shared__ ushortT lds[2][2 * 16384];   // [buf][A(16384) | B(16384)] = 128 KiB

  const int tid  = threadIdx.x;           // 0..511
  const int lane = tid & 63;
  const int wave = tid >> 6;              // 0..7
  const int wr   = wave >> 2;             // 0..1  (M)
  const int wc   = wave & 3;              // 0..3  (N)
  const int l15  = lane & 15;
  const int quad = lane >> 4;

  const ushortT* Ap = A;
  const ushortT* Bp = Bm;
  const float* biasP = bias;
  ushortT* CbP = Cb;
  if (DUALZ && blockIdx.z) { Ap = A2; Bp = Bm2; biasP = bias2; CbP = Cb2; }
  const long zA = DUALZ ? 0 : (long)blockIdx.z * aBatch;
  const long zB = DUALZ ? 0 : (long)blockIdx.z * bBatch;
  const long zC = DUALZ ? 0 : (long)blockIdx.z * cBatch;
  const int rowBase = (SWAP ? blockIdx.y : blockIdx.x) * 256;
  const int colBase = (SWAP ? blockIdx.x : blockIdx.y) * 256;

  // one A-load (chunk l of 4): covers A rows l*64..l*64+63
  auto STAGE_A = [&](int t, int l) {
    ushortT* sA = lds[t & 1];
    const int k0 = t << 6;
    int idx = l * 512 + tid;
    int row = idx >> 3;
    int ck  = ((tid & 7) ^ (row & 7)) << 3;
    if (CONV_A) {
      int gr = rowBase + row;
      int gc = k0 + ck;
      int tap = gc >> 9, ii = gc & 511;
      int b = gr >> 11, tt = gr & 2047;
      long gofs = ((long)(b * 2050 + tt + tap) << 9) + ii;
      gload_lds16(Ap + gofs, sA + idx * 8);
    } else {
      long gofs = zA + (long)(rowBase + row) * lda + (k0 + ck);
      gload_lds16(Ap + gofs, sA + idx * 8);
    }
  };
  auto STAGE_B = [&](int t, int l) {
    ushortT* sB = lds[t & 1] + 16384;
    const int k0 = t << 6;
    int idx = l * 512 + tid;
    int row = idx >> 3;
    int ck  = ((tid & 7) ^ (row & 7)) << 3;
    long gofs = zB + (long)(colBase + row) * ldb + (k0 + ck);
    gload_lds16(Bp + gofs, sB + idx * 8);
  };

  auto LD = [&](const ushortT* s, int r, int c) -> bf16x8 {
    return *(const bf16x8*)&s[r * 64 + ((c ^ (r & 7)) << 3)];
  };

  floatx4 zero = {0.f, 0.f, 0.f, 0.f};
  floatx4 acc[8][4];
#pragma unroll
  for (int mi = 0; mi < 8; mi++)
#pragma unroll
    for (int ni = 0; ni < 4; ni++) acc[mi][ni] = zero;

  const int NT = Kdim >> 6;
#pragma unroll
  for (int l = 0; l < 4; l++) { STAGE_B(0, l); }
#pragma unroll
  for (int l = 0; l < 4; l++) { STAGE_A(0, l); }
#pragma unroll
  for (int l = 0; l < 4; l++) { STAGE_B(1, l); }
#pragma unroll
  for (int l = 0; l < 4; l++) { STAGE_A(1, l); }

  for (int t = 0; t < NT; t++) {
    if (t < NT - 1) asm volatile("s_waitcnt vmcnt(8)" ::: "memory");
    else            asm volatile("s_waitcnt vmcnt(0)" ::: "memory");
    __builtin_amdgcn_s_barrier();

    const ushortT* sA = lds[t & 1];
    const ushortT* sB = sA + 16384;

    bf16x8 av[4][2], bv[4][2];
#pragma unroll
    for (int ni = 0; ni < 4; ni++)
#pragma unroll
      for (int ks = 0; ks < 2; ks++)
        bv[ni][ks] = LD(sB, wc * 64 + ni * 16 + l15, ks * 4 + quad);
#pragma unroll
    for (int mi = 0; mi < 4; mi++)
#pragma unroll
      for (int ks = 0; ks < 2; ks++)
        av[mi][ks] = LD(sA, wr * 128 + mi * 16 + l15, ks * 4 + quad);

    __builtin_amdgcn_s_setprio(1);
#pragma unroll
    for (int mi = 0; mi < 4; mi++)
#pragma unroll
      for (int ni = 0; ni < 4; ni++)
#pragma unroll
        for (int ks = 0; ks < 2; ks++)
          acc[mi][ni] = __builtin_amdgcn_mfma_f32_16x16x32_bf16(av[mi][ks], bv[ni][ks], acc[mi][ni], 0, 0, 0);
    __builtin_amdgcn_s_setprio(0);

    __builtin_amdgcn_s_barrier();   // all B reads + A quarters 0,2 consumed

    // cluster-1 fragment reads (A quarters 1,3 — disjoint from prefetch targets)
#pragma unroll
    for (int mi = 0; mi < 4; mi++)
#pragma unroll
      for (int ks = 0; ks < 2; ks++)
        av[mi][ks] = LD(sA, wr * 128 + 64 + mi * 16 + l15, ks * 4 + quad);

    if (t + 2 < NT) {   // 6 loads overlapped with cluster-1
      STAGE_B(t + 2, 0); STAGE_B(t + 2, 1); STAGE_B(t + 2, 2); STAGE_B(t + 2, 3);
      STAGE_A(t + 2, 0); STAGE_A(t + 2, 2);
    }

    __builtin_amdgcn_s_setprio(1);
#pragma unroll
    for (int mi = 0; mi < 4; mi++)
#pragma unroll
      for (int ni = 0; ni < 4; ni++)
#pragma unroll
        for (int ks = 0; ks < 2; ks++)
          acc[4 + mi][ni] = __builtin_amdgcn_mfma_f32_16x16x32_bf16(av[mi][ks], bv[ni][ks], acc[4 + mi][ni], 0, 0, 0);
    __builtin_amdgcn_s_setprio(0);

    __builtin_amdgcn_s_barrier();
    if (t + 2 < NT) { STAGE_A(t + 2, 1); STAGE_A(t + 2, 3); }
  }

  if (GLU) {
#pragma unroll
    for (int mi = 0; mi < 8; mi++) {
#pragma unroll
      for (int ni = 0; ni < 4; ni += 2) {
        int colA = colBase + wc * 64 + ni * 16;
        int d = (colA >> 5) * 16 + l15;
        float ba = biasP[d], bg = biasP[512 + d];
#pragma unroll
        for (int r = 0; r < 4; r++) {
          int grow = rowBase + wr * 128 + mi * 16 + quad * 4 + r;
          float a = acc[mi][ni][r] + ba;
          float g = acc[mi][ni + 1][r] + bg;
          float val = a / (1.0f + __expf(-g)) + xres[(long)grow * 512 + d];
          Cf[(long)grow * 512 + d] = val;
        }
      }
    }
  } else {
#pragma unroll
    for (int mi = 0; mi < 8; mi++) {
#pragma unroll
      for (int ni = 0; ni < 4; ni++) {
        int gcol = colBase + wc * 64 + ni * 16 + l15;
        float bcol = BIAS ? biasP[gcol] : 0.0f;
#pragma unroll
        for (int r = 0; r < 4; r++) {
          int grow = rowBase + wr * 128 + mi * 16 + quad * 4 + r;
          float val = acc[mi][ni][r] * scale + bcol;
          long off = zC + (long)grow * ldc + gcol;
          if (WBF16) CbP[off] = f2bf(val);
          else       Cf[off] = val;
        }
      }
    }
  }
}

// ---------------- 64x512 counted-vmcnt double-buffered GEMM (vT, oproj) ----------------
template<int BIAS, int WBF16, int LNEPI>
__global__ __launch_bounds__(512)
void k_gemm64(const ushortT* __restrict__ A, int lda, long aBatch,
              const ushortT* __restrict__ Bm, int ldb, long bBatch,
              const float* __restrict__ bias, const ushortT* __restrict__ hres,
              const float* __restrict__ lnw, const float* __restrict__ lnb,
              float* __restrict__ Cf, ushortT* __restrict__ Cb,
              long cBatch, int ldc, int Kdim, float scale)
{
  __shared__ ushortT lds[2][(64 + 512) * 64];   // 144 KiB

  const int tid  = threadIdx.x;           // 0..511
  const int lane = tid & 63;
  const int wave = tid >> 6;              // 0..7
  const int l15  = lane & 15;
  const int quad = lane >> 4;

  const long zA = (long)blockIdx.z * aBatch;
  const long zB = (long)blockIdx.z * bBatch;
  const long zC = (long)blockIdx.z * cBatch;
  const int rowBase = blockIdx.y * 64;
  const int colBase = blockIdx.x * 512;

  auto STAGE = [&](int t) {
    ushortT* sA = lds[t & 1];
    ushortT* sB = sA + 64 * 64;
    const int k0 = t << 6;
    {
      int row = tid >> 3;                 // 0..63
      int ck  = ((tid & 7) ^ (row & 7)) << 3;
      long gofs = zA + (long)(rowBase + row) * lda + (k0 + ck);
      gload_lds16(A + gofs, sA + tid * 8);
    }
#pragma unroll
    for (int l = 0; l < 8; l++) {
      int idx = l * 512 + tid;            // 0..4095
      int row = idx >> 3;                 // 0..511
      int ck  = ((tid & 7) ^ (row & 7)) << 3;
      long gofs = zB + (long)(colBase + row) * ldb + (k0 + ck);
      gload_lds16(Bm + gofs, sB + idx * 8);
    }
  };

  auto LD = [&](const ushortT* s, int r, int c) -> bf16x8 {
    return *(const bf16x8*)&s[r * 64 + ((c ^ (r & 7)) << 3)];
  };

  floatx4 zero = {0.f, 0.f, 0.f, 0.f};
  floatx4 acc[4][4];
#pragma unroll
  for (int mi = 0; mi < 4; mi++)
#pragma unroll
    for (int ni = 0; ni < 4; ni++) acc[mi][ni] = zero;

  const int NT = Kdim >> 6;
  STAGE(0);
  STAGE(1);

  for (int t = 0; t < NT; t++) {
    if (t < NT - 1) asm volatile("s_waitcnt vmcnt(9)" ::: "memory");
    else            asm volatile("s_waitcnt vmcnt(0)" ::: "memory");
    __builtin_amdgcn_s_barrier();

    const ushortT* sA = lds[t & 1];
    const ushortT* sB = sA + 64 * 64;

    bf16x8 av[4][2], bv[4][2];
#pragma unroll
    for (int ni = 0; ni < 4; ni++)
#pragma unroll
      for (int ks = 0; ks < 2; ks++)
        bv[ni][ks] = LD(sB, wave * 64 + ni * 16 + l15, ks * 4 + quad);
#pragma unroll
    for (int mi = 0; mi < 4; mi++)
#pragma unroll
      for (int ks = 0; ks < 2; ks++)
        av[mi][ks] = LD(sA, mi * 16 + l15, ks * 4 + quad);

    __builtin_amdgcn_s_setprio(1);
#pragma unroll
    for (int mi = 0; mi < 4; mi++)
#pragma unroll
      for (int ni = 0; ni < 4; ni++)
#pragma unroll
        for (int ks = 0; ks < 2; ks++)
          acc[mi][ni] = __builtin_amdgcn_mfma_f32_16x16x32_bf16(av[mi][ks], bv[ni][ks], acc[mi][ni], 0, 0, 0);
    __builtin_amdgcn_s_setprio(0);

    __builtin_amdgcn_s_barrier();
    if (t + 2 < NT) STAGE(t + 2);
  }

  if (LNEPI) {
    float bov[4], lw[4], lb[4];
#pragma unroll
    for (int ni = 0; ni < 4; ni++) {
      int col = wave * 64 + ni * 16 + l15;
      bov[ni] = bias[col]; lw[ni] = lnw[col]; lb[ni] = lnb[col];
    }
    float* psum = (float*)&lds[0][0];
    float* pssq = psum + 8 * 64;
    __syncthreads();
#pragma unroll
    for (int mi = 0; mi < 4; mi++) {
#pragma unroll
      for (int r = 0; r < 4; r++) {
        int rowl = mi * 16 + quad * 4 + r;
        long grow = rowBase + rowl;
        float ps = 0.f, pq = 0.f;
#pragma unroll
        for (int ni = 0; ni < 4; ni++) {
          int col = wave * 64 + ni * 16 + l15;
          float val = acc[mi][ni][r] + bov[ni] + bf2f(hres[grow * 512 + col]);
          acc[mi][ni][r] = val;
          ps += val; pq += val * val;
        }
#pragma unroll
        for (int off = 1; off < 16; off <<= 1) { ps += __shfl_xor(ps, off); pq += __shfl_xor(pq, off); }
        if (l15 == 0) { psum[wave * 64 + rowl] = ps; pssq[wave * 64 + rowl] = pq; }
      }
    }
    __syncthreads();
#pragma unroll
    for (int mi = 0; mi < 4; mi++) {
#pragma unroll
      for (int r = 0; r < 4; r++) {
        int rowl = mi * 16 + quad * 4 + r;
        float S = 0.f, Q = 0.f;
#pragma unroll
        for (int w = 0; w < 8; w++) { S += psum[w * 64 + rowl]; Q += pssq[w * 64 + rowl]; }
        float mu = S * (1.0f / 512.0f);
        float rstd = rsqrtf(Q * (1.0f / 512.0f) - mu * mu + 1e-5f);
        long grow = rowBase + rowl;
#pragma unroll
        for (int ni = 0; ni < 4; ni++) {
          int col = wave * 64 + ni * 16 + l15;
          Cf[grow * 512 + col] = (acc[mi][ni][r] - mu) * rstd * lw[ni] + lb[ni];
        }
      }
    }
  } else {
#pragma unroll
    for (int mi = 0; mi < 4; mi++) {
#pragma unroll
      for (int ni = 0; ni < 4; ni++) {
        int gcol = colBase + wave * 64 + ni * 16 + l15;
        float bcol = (BIAS == 1) ? bias[gcol] : 0.0f;
#pragma unroll
        for (int r = 0; r < 4; r++) {
          int grow = rowBase + mi * 16 + quad * 4 + r;
          float val = acc[mi][ni][r] * scale + bcol + ((BIAS == 2) ? bias[grow] : 0.0f);
          long off = zC + (long)grow * ldc + gcol;
          if (WBF16) Cb[off] = f2bf(val);
          else       Cf[off] = val;
        }
      }
    }
  }
}

// ---------------- fused softmax + ctx = softmax(logits) @ V ----------------
// Block owns 64 rows x full S=2048 (K dim). Prepass: row max + exp-sum.
// Main loop: B (vT) via gload_lds; A reg-staged with exp/normalize transform
// (T14 issue-early/write-late), attn fp32 written as a side effect.
__global__ __launch_bounds__(512)
void k_ctx_sm(const ushortT* __restrict__ logit,   // [B*T, 2048] bf16
              const ushortT* __restrict__ vT,      // [512][16384]
              float* __restrict__ attn,            // [B*T, 2048] f32
              ushortT* __restrict__ ctxb)          // [B*T, 512] bf16
{
  __shared__ ushortT sB[2][512 * 64];   // 128 KiB
  __shared__ ushortT sA[2][64 * 64];    // 16 KiB
  __shared__ float rowM[64], rowInv[64];

  const int tid = threadIdx.x, lane = tid & 63, wave = tid >> 6;
  const int l15 = lane & 15, quad = lane >> 4;
  const int z = blockIdx.z;
  const int rowBase = blockIdx.y * 64;
  const long lrowBase = (long)z * 2048 + rowBase;

  // ---- prepass: per-row max, then exp-sum (8 threads per row) ----
  {
    int r = tid >> 3, c0 = (tid & 7) * 256;
    const ushortT* lp = logit + (lrowBase + r) * 2048 + c0;
    float m = -3.0e38f;
    for (int i = 0; i < 32; i++) {
      ushort8 u = *(const ushort8*)&lp[i * 8];
#pragma unroll
      for (int j = 0; j < 8; j++) m = fmaxf(m, bf2f(u[j]));
    }
    m = fmaxf(m, __shfl_xor(m, 1));
    m = fmaxf(m, __shfl_xor(m, 2));
    m = fmaxf(m, __shfl_xor(m, 4));
    float s = 0.f;
    for (int i = 0; i < 32; i++) {
      ushort8 u = *(const ushort8*)&lp[i * 8];
#pragma unroll
      for (int j = 0; j < 8; j++) s += __expf(bf2f(u[j]) - m);
    }
    s += __shfl_xor(s, 1);
    s += __shfl_xor(s, 2);
    s += __shfl_xor(s, 4);
    if ((tid & 7) == 0) { rowM[r] = m; rowInv[r] = 1.0f / s; }
  }
  __syncthreads();

  const int rA = tid >> 3, cA = tid & 7;
  const float Mr = rowM[rA], Ir = rowInv[rA];

  auto STAGEB = [&](int t) {
    ushortT* d = sB[t & 1];
    const int k0 = t << 6;
#pragma unroll
    for (int l = 0; l < 8; l++) {
      int idx = l * 512 + tid;
      int row = idx >> 3;
      int ck = ((tid & 7) ^ (row & 7)) << 3;
      long gofs = (long)row * 16384 + (long)z * 2048 + k0 + ck;
      gload_lds16(vT + gofs, d + idx * 8);
    }
  };
  auto ALOAD = [&](int t) -> ushort8 {
    return *(const ushort8*)&logit[(lrowBase + rA) * 2048 + (t << 6) + cA * 8];
  };
  auto APUT = [&](int t, ushort8 u) {
    floatx4 p0, p1;
    ushort8 pb;
#pragma unroll
    for (int j = 0; j < 8; j++) {
      float p = __expf(bf2f(u[j]) - Mr) * Ir;
      if (j < 4) p0[j] = p; else p1[j - 4] = p;
      pb[j] = f2bf(p);
    }
    float* ap = attn + (lrowBase + rA) * 2048 + (t << 6) + cA * 8;
    *(floatx4*)ap = p0;
    *(floatx4*)(ap + 4) = p1;
    *(ushort8*)&sA[t & 1][rA * 64 + ((cA ^ (rA & 7)) << 3)] = pb;
  };
  auto LD = [&](const ushortT* s, int r, int c) -> bf16x8 {
    return *(const bf16x8*)&s[r * 64 + ((c ^ (r & 7)) << 3)];
  };

  floatx4 zero = {0.f, 0.f, 0.f, 0.f};
  floatx4 acc[4][4];
#pragma unroll
  for (int mi = 0; mi < 4; mi++)
#pragma unroll
    for (int ni = 0; ni < 4; ni++) acc[mi][ni] = zero;

  const int NT = 32;   // K = 2048
  ushort8 aCur = ALOAD(0); STAGEB(0);
  ushort8 aNxt = ALOAD(1); STAGEB(1);
  APUT(0, aCur);                                   // compiler waits aCur
  asm volatile("s_waitcnt vmcnt(9)" ::: "memory"); // B0 landed (newest 9 = a1+B1)
  asm volatile("s_waitcnt lgkmcnt(0)" ::: "memory");
  __builtin_amdgcn_s_barrier();

  ushort8 aNew = aNxt;
  for (int t = 0; t < NT; t++) {
    const ushortT* cA_ = sA[t & 1];
    const ushortT* cB_ = sB[t & 1];
    bf16x8 av[4][2], bv[4][2];
#pragma unroll
    for (int ni = 0; ni < 4; ni++)
#pragma unroll
      for (int ks = 0; ks < 2; ks++)
        bv[ni][ks] = LD(cB_, wave * 64 + ni * 16 + l15, ks * 4 + quad);
#pragma unroll
    for (int mi = 0; mi < 4; mi++)
#pragma unroll
      for (int ks = 0; ks < 2; ks++)
        av[mi][ks] = LD(cA_, mi * 16 + l15, ks * 4 + quad);

    __builtin_amdgcn_s_setprio(1);
#pragma unroll
    for (int mi = 0; mi < 4; mi++)
#pragma unroll
      for (int ni = 0; ni < 4; ni++)
#pragma unroll
        for (int ks = 0; ks < 2; ks++)
          acc[mi][ni] = __builtin_amdgcn_mfma_f32_16x16x32_bf16(av[mi][ks], bv[ni][ks], acc[mi][ni], 0, 0, 0);
    __builtin_amdgcn_s_setprio(0);

    __builtin_amdgcn_s_barrier();        // all waves done reading buf[t&1]
    if (t + 2 < NT) { aNew = ALOAD(t + 2); STAGEB(t + 2); }  // -> buf[t&1]
    if (t + 1 < NT) {
      if (t + 2 < NT) asm volatile("s_waitcnt vmcnt(9)" ::: "memory");
      else            asm volatile("s_waitcnt vmcnt(0)" ::: "memory");
      APUT(t + 1, aNxt);                 // -> sA[(t+1)&1] (not being read)
      aNxt = aNew;
      asm volatile("s_waitcnt lgkmcnt(0)" ::: "memory");
    }
    __builtin_amdgcn_s_barrier();        // buf[(t+1)&1] ready
  }

  // epilogue: ctx bf16 [row][512]
#pragma unroll
  for (int mi = 0; mi < 4; mi++) {
#pragma unroll
    for (int ni = 0; ni < 4; ni++) {
      int col = wave * 64 + ni * 16 + l15;
#pragma unroll
      for (int r = 0; r < 4; r++) {
        long grow = lrowBase + mi * 16 + quad * 4 + r;
        ctxb[grow * 512 + col] = f2bf(acc[mi][ni][r]);
      }
    }
  }
}

// ---------------- LN1 -> bf16 only ----------------
__global__ __launch_bounds__(128)
void k_ln(const float* __restrict__ src, const float* __restrict__ w, const float* __restrict__ b,
          ushortT* __restrict__ outb)
{
  __shared__ float s1[2], s2[2];
  long r = blockIdx.x;
  int tid = threadIdx.x;
  floatx4 v = *(const floatx4*)&src[r * 512 + tid * 4];
  float sum = v[0] + v[1] + v[2] + v[3];
  float ssq = v[0]*v[0] + v[1]*v[1] + v[2]*v[2] + v[3]*v[3];
#pragma unroll
  for (int off = 32; off; off >>= 1) { sum += __shfl_xor(sum, off); ssq += __shfl_xor(ssq, off); }
  if ((tid & 63) == 0) { s1[tid >> 6] = sum; s2[tid >> 6] = ssq; }
  __syncthreads();
  sum = s1[0] + s1[1]; ssq = s2[0] + s2[1];
  float mu = sum * (1.0f / 512.0f);
  float var = ssq * (1.0f / 512.0f) - mu * mu;
  float rstd = rsqrtf(var + 1e-5f);
  floatx4 wv = *(const floatx4*)&w[tid * 4];
  floatx4 bv = *(const floatx4*)&b[tid * 4];
  ushort4v ob;
#pragma unroll
  for (int j = 0; j < 4; j++) ob[j] = f2bf((v[j] - mu) * rstd * wv[j] + bv[j]);
  *(ushort4v*)&outb[r * 512 + tid * 4] = ob;
}

extern "C" void kernel_launch(void* const* d_in, const int* in_sizes, int n_in,
                              void* d_out, int out_size, void* d_ws, size_t ws_size,
                              hipStream_t stream)
{
  const float* x      = (const float*)d_in[0];
  const float* enc    = (const float*)d_in[1];
  const float* conv_w = (const float*)d_in[2];
  const float* conv_b = (const float*)d_in[3];
  const float* ln1_w  = (const float*)d_in[4];
  const float* ln1_b  = (const float*)d_in[5];
  const float* Wq     = (const float*)d_in[6];
  const float* bq     = (const float*)d_in[7];
  const float* Wk     = (const float*)d_in[8];
  const float* bk     = (const float*)d_in[9];
  const float* Wv     = (const float*)d_in[10];
  const float* bv     = (const float*)d_in[11];
  const float* Wo     = (const float*)d_in[12];
  const float* bo     = (const float*)d_in[13];
  const float* ln2_w  = (const float*)d_in[14];
  const float* ln2_b  = (const float*)d_in[15];

  const long BT = 16384, Dd = 512, S = 2048, TT = 2048;
  float* out  = (float*)d_out;
  float* attn = out + BT * Dd;

  char* p = (char*)d_ws;
  auto alloc = [&](size_t bytes) { char* r = p; p += (bytes + 255) & ~255UL; return r; };
  float*   hglu  = (float*)alloc(BT * Dd * 4);
  ushortT* xpad  = (ushortT*)alloc(8L * 2050 * 512 * 2);
  ushortT* encbf = (ushortT*)alloc(BT * Dd * 2);
  ushortT* hbf   = (ushortT*)alloc(BT * Dd * 2);
  ushortT* qbf   = (ushortT*)alloc(BT * Dd * 2);
  ushortT* kbf   = (ushortT*)alloc(BT * Dd * 2);
  ushortT* vT    = (ushortT*)alloc(Dd * BT * 2);    // [512][16384]
  ushortT* ctxbf = (ushortT*)alloc(BT * Dd * 2);
  ushortT* sl    = (ushortT*)alloc(BT * S * 2);     // bf16 logits
  ushortT* Wcbf  = (ushortT*)alloc(1024L * 1536 * 2);
  ushortT* wall  = (ushortT*)alloc(4L * 262144 * 2);
  ushortT* Wqbf = wall, *Wkbf = wall + 262144, *Wvbf = wall + 2 * 262144, *Wobf = wall + 3 * 262144;

  // conversions
  k_xpad<<<8 * 2050, 128, 0, stream>>>(x, xpad);
  k_f32_to_bf16v<<<(BT * Dd / 4 + 255) / 256, 256, 0, stream>>>(enc, encbf, BT * Dd / 4);
  k_convw<<<(1024 * 1536 + 255) / 256, 256, 0, stream>>>(conv_w, Wcbf);
  k_w4<<<1024, 256, 0, stream>>>(Wq, Wk, Wv, Wo, wall);

  // conv GEMM + fused GLU + residual -> hglu fp32   (M=16384, N=1024, K=1536)
  k_gemm256<1, 1, 0, 0, 0, 0><<<dim3(64, 4, 1), 512, 0, stream>>>(
      xpad, nullptr, 0, 0, Wcbf, nullptr, 1536, 0,
      conv_b, nullptr, x, hglu, nullptr, nullptr, 0, 512, 1536, 1.0f);
  // LN1 -> hbf bf16
  k_ln<<<16384, 128, 0, stream>>>(hglu, ln1_w, ln1_b, hbf);

  // q = h @ Wq^T + bq  (z=0)  ||  k = enc @ Wk^T + bk  (z=1)
  k_gemm256<0, 0, 1, 1, 1, 0><<<dim3(64, 2, 2), 512, 0, stream>>>(
      hbf, encbf, 512, 0, Wqbf, Wkbf, 512, 0,
      bq, bk, nullptr, nullptr, qbf, kbf, 0, 512, 512, 1.0f);

  // vT = Wv @ enc^T + bv (row bias) -> [512][16384]
  k_gemm64<2, 1, 0><<<dim3(32, 8, 1), 512, 0, stream>>>(
      Wvbf, 512, 0, encbf, 512, 0,
      bv, nullptr, nullptr, nullptr,
      nullptr, vT, 0, 16384, 512, 1.0f);

  // scores -> bf16 logits in sl  (per batch 2048x2048, K=512)
  k_gemm256<0, 0, 0, 1, 0, 0><<<dim3(8, 8, 8), 512, 0, stream>>>(
      qbf, nullptr, 512, TT * Dd, kbf, nullptr, 512, S * Dd,
      nullptr, nullptr, nullptr, nullptr, sl, nullptr,
      TT * S, 2048, 512, 0.04419417382415922f);

  // fused softmax + ctx: attn fp32 out + ctx bf16
  k_ctx_sm<<<dim3(1, 32, 8), 512, 0, stream>>>(sl, vT, attn, ctxbf);

  // fused out-proj + residual + LN2 -> out  (M=16384: 256 blocks, BN=512 full row)
  k_gemm64<0, 0, 1><<<dim3(1, 256, 1), 512, 0, stream>>>(
      ctxbf, 512, 0, Wobf, 512, 0,
      bo, hbf, ln2_w, ln2_b,
      out, nullptr, 0, 512, 512, 1.0f);
}

// Round 4
// 499.435 us; speedup vs baseline: 1.0790x; 1.0790x over previous
//
#include <hip/hip_runtime.h>
#include <hip/hip_bf16.h>
#include <stdint.h>

// ConvDecoderLayer: B=8, T=S=2048, D=512, K=3
// out = (LN2(h + (attn@v)@Wo^T + bo), attn), h = LN1(GLU(causal_conv(x)) + x)

typedef unsigned short ushortT;
typedef __bf16 bf16x8 __attribute__((ext_vector_type(8)));
typedef float floatx4 __attribute__((ext_vector_type(4)));
typedef unsigned short ushort4v __attribute__((ext_vector_type(4)));
typedef unsigned short ushort8 __attribute__((ext_vector_type(8)));

__device__ __forceinline__ ushortT f2bf(float f) {
  unsigned u = __builtin_bit_cast(unsigned, f);
  u += 0x7FFFu + ((u >> 16) & 1u);   // RNE
  return (ushortT)(u >> 16);
}
__device__ __forceinline__ float bf2f(ushortT u) {
  return __builtin_bit_cast(float, (unsigned)u << 16);
}

__device__ __forceinline__ void gload_lds16(const void* g, void* l) {
  __builtin_amdgcn_global_load_lds(
      (const __attribute__((address_space(1))) void*)g,
      (__attribute__((address_space(3))) void*)l, 16, 0, 0);
}

// ---------------- conversion kernels ----------------
__global__ __launch_bounds__(256)
void k_f32_to_bf16v(const float* __restrict__ src, ushortT* __restrict__ dst, long n4) {
  long i = (long)blockIdx.x * 256 + threadIdx.x;
  if (i >= n4) return;
  floatx4 v = *(const floatx4*)&src[i * 4];
  ushort4v o;
#pragma unroll
  for (int j = 0; j < 4; j++) o[j] = f2bf(v[j]);
  *(ushort4v*)&dst[i * 4] = o;
}

// four 512x512 weights -> bf16, one launch
__global__ __launch_bounds__(256)
void k_w4(const float* __restrict__ w0, const float* __restrict__ w1,
          const float* __restrict__ w2, const float* __restrict__ w3,
          ushortT* __restrict__ dst) {
  long i = (long)blockIdx.x * 256 + threadIdx.x;   // float4 groups, 4*65536 total
  int m = (int)(i >> 16);
  long within = (i & 65535) * 4;
  const float* s = (m == 0) ? w0 : (m == 1) ? w1 : (m == 2) ? w2 : w3;
  floatx4 v = *(const floatx4*)&s[within];
  ushort4v o;
#pragma unroll
  for (int j = 0; j < 4; j++) o[j] = f2bf(v[j]);
  *(ushort4v*)&dst[(long)m * 262144 + within] = o;
}

// x [8,2048,512] f32 -> xpad [8,2050,512] bf16 with 2 leading zero rows per batch
__global__ __launch_bounds__(128)
void k_xpad(const float* __restrict__ x, ushortT* __restrict__ xp) {
  int row = blockIdx.x;                 // 8*2050
  int b = row / 2050, tp = row % 2050;
  int c = threadIdx.x * 4;
  ushort4v o = {0, 0, 0, 0};
  if (tp >= 2) {
    floatx4 v = *(const floatx4*)&x[((long)(b * 2048 + tp - 2)) * 512 + c];
#pragma unroll
    for (int j = 0; j < 4; j++) o[j] = f2bf(v[j]);
  }
  *(ushort4v*)&xp[(long)row * 512 + c] = o;
}

// conv_w [1024][512][3] -> interleaved B^T form Wc'[n][kk], kk = tap*512+i
__global__ __launch_bounds__(256)
void k_convw(const float* __restrict__ w, ushortT* __restrict__ dst) {
  long idx = (long)blockIdx.x * 256 + threadIdx.x;
  if (idx >= 1024L * 1536) return;
  int n = (int)(idx / 1536), kk = (int)(idx % 1536);
  int tap = kk >> 9, i = kk & 511;
  int o = ((n >> 4) & 1) * 512 + (n >> 5) * 16 + (n & 15);
  dst[idx] = f2bf(w[(o * 512 + i) * 3 + tap]);
}

// ---------------- 256x256 phased counted-vmcnt GEMM ----------------
// 8 waves (2M x 4N), BK=64, 128 KiB LDS. T2 swizzle + T3/T4 counted vmcnt + T5.
template<int CONV_A, int GLU, int BIAS, int WBF16, int DUALZ, int SWAP>
__global__ __launch_bounds__(512)
void k_gemm256(const ushortT* __restrict__ A, const ushortT* __restrict__ A2, int lda, long aBatch,
               const ushortT* __restrict__ Bm, const ushortT* __restrict__ Bm2, int ldb, long bBatch,
               const float* __restrict__ bias, const float* __restrict__ bias2,
               const float* __restrict__ xres,
               float* __restrict__ Cf, ushortT* __restrict__ Cb, ushortT* __restrict__ Cb2,
               long cBatch, int ldc, int Kdim, float scale)
{
  __shared__ ushortT lds[2][2 * 16384];   // [buf][A(16384) | B(16384)] = 128 KiB

  const int tid  = threadIdx.x;           // 0..511
  const int lane = tid & 63;
  const int wave = tid >> 6;              // 0..7
  const int wr   = wave >> 2;             // 0..1  (M)
  const int wc   = wave & 3;              // 0..3  (N)
  const int l15  = lane & 15;
  const int quad = lane >> 4;

  const ushortT* Ap = A;
  const ushortT* Bp = Bm;
  const float* biasP = bias;
  ushortT* CbP = Cb;
  if (DUALZ && blockIdx.z) { Ap = A2; Bp = Bm2; biasP = bias2; CbP = Cb2; }
  const long zA = DUALZ ? 0 : (long)blockIdx.z * aBatch;
  const long zB = DUALZ ? 0 : (long)blockIdx.z * bBatch;
  const long zC = DUALZ ? 0 : (long)blockIdx.z * cBatch;
  const int rowBase = (SWAP ? blockIdx.y : blockIdx.x) * 256;
  const int colBase = (SWAP ? blockIdx.x : blockIdx.y) * 256;

  auto STAGE_A = [&](int t, int l) {
    ushortT* sA = lds[t & 1];
    const int k0 = t << 6;
    int idx = l * 512 + tid;
    int row = idx >> 3;
    int ck  = ((tid & 7) ^ (row & 7)) << 3;
    if (CONV_A) {
      int gr = rowBase + row;
      int gc = k0 + ck;
      int tap = gc >> 9, ii = gc & 511;
      int b = gr >> 11, tt = gr & 2047;
      long gofs = ((long)(b * 2050 + tt + tap) << 9) + ii;
      gload_lds16(Ap + gofs, sA + idx * 8);
    } else {
      long gofs = zA + (long)(rowBase + row) * lda + (k0 + ck);
      gload_lds16(Ap + gofs, sA + idx * 8);
    }
  };
  auto STAGE_B = [&](int t, int l) {
    ushortT* sB = lds[t & 1] + 16384;
    const int k0 = t << 6;
    int idx = l * 512 + tid;
    int row = idx >> 3;
    int ck  = ((tid & 7) ^ (row & 7)) << 3;
    long gofs = zB + (long)(colBase + row) * ldb + (k0 + ck);
    gload_lds16(Bp + gofs, sB + idx * 8);
  };

  auto LD = [&](const ushortT* s, int r, int c) -> bf16x8 {
    return *(const bf16x8*)&s[r * 64 + ((c ^ (r & 7)) << 3)];
  };

  floatx4 zero = {0.f, 0.f, 0.f, 0.f};
  floatx4 acc[8][4];
#pragma unroll
  for (int mi = 0; mi < 8; mi++)
#pragma unroll
    for (int ni = 0; ni < 4; ni++) acc[mi][ni] = zero;

  const int NT = Kdim >> 6;
#pragma unroll
  for (int l = 0; l < 4; l++) { STAGE_B(0, l); }
#pragma unroll
  for (int l = 0; l < 4; l++) { STAGE_A(0, l); }
#pragma unroll
  for (int l = 0; l < 4; l++) { STAGE_B(1, l); }
#pragma unroll
  for (int l = 0; l < 4; l++) { STAGE_A(1, l); }

  for (int t = 0; t < NT; t++) {
    if (t < NT - 1) asm volatile("s_waitcnt vmcnt(8)" ::: "memory");
    else            asm volatile("s_waitcnt vmcnt(0)" ::: "memory");
    __builtin_amdgcn_s_barrier();

    const ushortT* sA = lds[t & 1];
    const ushortT* sB = sA + 16384;

    bf16x8 av[4][2], bv[4][2];
#pragma unroll
    for (int ni = 0; ni < 4; ni++)
#pragma unroll
      for (int ks = 0; ks < 2; ks++)
        bv[ni][ks] = LD(sB, wc * 64 + ni * 16 + l15, ks * 4 + quad);
#pragma unroll
    for (int mi = 0; mi < 4; mi++)
#pragma unroll
      for (int ks = 0; ks < 2; ks++)
        av[mi][ks] = LD(sA, wr * 128 + mi * 16 + l15, ks * 4 + quad);

    __builtin_amdgcn_s_setprio(1);
#pragma unroll
    for (int mi = 0; mi < 4; mi++)
#pragma unroll
      for (int ni = 0; ni < 4; ni++)
#pragma unroll
        for (int ks = 0; ks < 2; ks++)
          acc[mi][ni] = __builtin_amdgcn_mfma_f32_16x16x32_bf16(av[mi][ks], bv[ni][ks], acc[mi][ni], 0, 0, 0);
    __builtin_amdgcn_s_setprio(0);

    __builtin_amdgcn_s_barrier();   // all B reads + A quarters 0,2 consumed

#pragma unroll
    for (int mi = 0; mi < 4; mi++)
#pragma unroll
      for (int ks = 0; ks < 2; ks++)
        av[mi][ks] = LD(sA, wr * 128 + 64 + mi * 16 + l15, ks * 4 + quad);

    if (t + 2 < NT) {   // 6 loads overlapped with cluster-1
      STAGE_B(t + 2, 0); STAGE_B(t + 2, 1); STAGE_B(t + 2, 2); STAGE_B(t + 2, 3);
      STAGE_A(t + 2, 0); STAGE_A(t + 2, 2);
    }

    __builtin_amdgcn_s_setprio(1);
#pragma unroll
    for (int mi = 0; mi < 4; mi++)
#pragma unroll
      for (int ni = 0; ni < 4; ni++)
#pragma unroll
        for (int ks = 0; ks < 2; ks++)
          acc[4 + mi][ni] = __builtin_amdgcn_mfma_f32_16x16x32_bf16(av[mi][ks], bv[ni][ks], acc[4 + mi][ni], 0, 0, 0);
    __builtin_amdgcn_s_setprio(0);

    __builtin_amdgcn_s_barrier();
    if (t + 2 < NT) { STAGE_A(t + 2, 1); STAGE_A(t + 2, 3); }
  }

  if (GLU) {
#pragma unroll
    for (int mi = 0; mi < 8; mi++) {
#pragma unroll
      for (int ni = 0; ni < 4; ni += 2) {
        int colA = colBase + wc * 64 + ni * 16;
        int d = (colA >> 5) * 16 + l15;
        float ba = biasP[d], bg = biasP[512 + d];
#pragma unroll
        for (int r = 0; r < 4; r++) {
          int grow = rowBase + wr * 128 + mi * 16 + quad * 4 + r;
          float a = acc[mi][ni][r] + ba;
          float g = acc[mi][ni + 1][r] + bg;
          float val = a / (1.0f + __expf(-g)) + xres[(long)grow * 512 + d];
          Cf[(long)grow * 512 + d] = val;
        }
      }
    }
  } else {
#pragma unroll
    for (int mi = 0; mi < 8; mi++) {
#pragma unroll
      for (int ni = 0; ni < 4; ni++) {
        int gcol = colBase + wc * 64 + ni * 16 + l15;
        float bcol = BIAS ? biasP[gcol] : 0.0f;
#pragma unroll
        for (int r = 0; r < 4; r++) {
          int grow = rowBase + wr * 128 + mi * 16 + quad * 4 + r;
          float val = acc[mi][ni][r] * scale + bcol;
          long off = zC + (long)grow * ldc + gcol;
          if (WBF16) CbP[off] = f2bf(val);
          else       Cf[off] = val;
        }
      }
    }
  }
}

// ---------------- ctx = P @ V : 128x256-tile counted-vmcnt GEMM ----------------
// BM=128, BN=256, BK=64; 8 waves (2M x 4N, 64x64 each); 96 KiB LDS.
// Grid: 256 linear blocks, XCD-swizzled so each XCD owns one batch ->
// vT panel (2 MB) fetched once per XCD-L2 instead of 8x.
__global__ __launch_bounds__(512)
void k_ctx128(const ushortT* __restrict__ P,    // [8*2048, 2048] bf16 (softmaxed)
              const ushortT* __restrict__ vT,   // [512][16384] bf16
              ushortT* __restrict__ ctxb)       // [8*2048, 512] bf16
{
  __shared__ ushortT lds[2][(128 + 256) * 64];   // 96 KiB

  const int tid  = threadIdx.x;
  const int lane = tid & 63;
  const int wave = tid >> 6;
  const int wr   = wave >> 2;             // 0..1
  const int wc   = wave & 3;              // 0..3
  const int l15  = lane & 15;
  const int quad = lane >> 4;

  const int lid = blockIdx.x;             // 0..255
  const int z   = lid & 7;                // batch == XCD
  const int idx = lid >> 3;               // 0..31
  const int rowBase = (idx >> 1) * 128;   // 16 M-tiles
  const int colBase = (idx & 1) * 256;    // 2 N-tiles
  const long zA = (long)z * 2048 * 2048;

  auto STAGE = [&](int t) {
    ushortT* sA = lds[t & 1];
    ushortT* sB = sA + 128 * 64;
    const int k0 = t << 6;
#pragma unroll
    for (int l = 0; l < 2; l++) {
      int i2 = l * 512 + tid;             // 0..1023
      int row = i2 >> 3;                  // 0..127
      int ck  = ((tid & 7) ^ (row & 7)) << 3;
      long gofs = zA + (long)(rowBase + row) * 2048 + (k0 + ck);
      gload_lds16(P + gofs, sA + i2 * 8);
    }
#pragma unroll
    for (int l = 0; l < 4; l++) {
      int i2 = l * 512 + tid;             // 0..2047
      int row = i2 >> 3;                  // 0..255
      int ck  = ((tid & 7) ^ (row & 7)) << 3;
      long gofs = (long)(colBase + row) * 16384 + (long)z * 2048 + (k0 + ck);
      gload_lds16(vT + gofs, sB + i2 * 8);
    }
  };

  auto LD = [&](const ushortT* s, int r, int c) -> bf16x8 {
    return *(const bf16x8*)&s[r * 64 + ((c ^ (r & 7)) << 3)];
  };

  floatx4 zero = {0.f, 0.f, 0.f, 0.f};
  floatx4 acc[4][4];
#pragma unroll
  for (int mi = 0; mi < 4; mi++)
#pragma unroll
    for (int ni = 0; ni < 4; ni++) acc[mi][ni] = zero;

  const int NT = 32;                      // K = 2048
  STAGE(0);
  STAGE(1);

  for (int t = 0; t < NT; t++) {
    if (t < NT - 1) asm volatile("s_waitcnt vmcnt(6)" ::: "memory");
    else            asm volatile("s_waitcnt vmcnt(0)" ::: "memory");
    __builtin_amdgcn_s_barrier();

    const ushortT* sA = lds[t & 1];
    const ushortT* sB = sA + 128 * 64;

    bf16x8 av[4][2], bv[4][2];
#pragma unroll
    for (int ni = 0; ni < 4; ni++)
#pragma unroll
      for (int ks = 0; ks < 2; ks++)
        bv[ni][ks] = LD(sB, wc * 64 + ni * 16 + l15, ks * 4 + quad);
#pragma unroll
    for (int mi = 0; mi < 4; mi++)
#pragma unroll
      for (int ks = 0; ks < 2; ks++)
        av[mi][ks] = LD(sA, wr * 64 + mi * 16 + l15, ks * 4 + quad);

    __builtin_amdgcn_s_setprio(1);
#pragma unroll
    for (int mi = 0; mi < 4; mi++)
#pragma unroll
      for (int ni = 0; ni < 4; ni++)
#pragma unroll
        for (int ks = 0; ks < 2; ks++)
          acc[mi][ni] = __builtin_amdgcn_mfma_f32_16x16x32_bf16(av[mi][ks], bv[ni][ks], acc[mi][ni], 0, 0, 0);
    __builtin_amdgcn_s_setprio(0);

    __builtin_amdgcn_s_barrier();
    if (t + 2 < NT) STAGE(t + 2);
  }

#pragma unroll
  for (int mi = 0; mi < 4; mi++) {
#pragma unroll
    for (int ni = 0; ni < 4; ni++) {
      int col = colBase + wc * 64 + ni * 16 + l15;
#pragma unroll
      for (int r = 0; r < 4; r++) {
        long grow = (long)z * 2048 + rowBase + wr * 64 + mi * 16 + quad * 4 + r;
        ctxb[grow * 512 + col] = f2bf(acc[mi][ni][r]);
      }
    }
  }
}

// ---------------- 64x512 counted-vmcnt double-buffered GEMM (vT, oproj) ----------------
template<int BIAS, int WBF16, int LNEPI>
__global__ __launch_bounds__(512)
void k_gemm64(const ushortT* __restrict__ A, int lda, long aBatch,
              const ushortT* __restrict__ Bm, int ldb, long bBatch,
              const float* __restrict__ bias, const ushortT* __restrict__ hres,
              const float* __restrict__ lnw, const float* __restrict__ lnb,
              float* __restrict__ Cf, ushortT* __restrict__ Cb,
              long cBatch, int ldc, int Kdim, float scale)
{
  __shared__ ushortT lds[2][(64 + 512) * 64];   // 144 KiB

  const int tid  = threadIdx.x;           // 0..511
  const int lane = tid & 63;
  const int wave = tid >> 6;              // 0..7
  const int l15  = lane & 15;
  const int quad = lane >> 4;

  const long zA = (long)blockIdx.z * aBatch;
  const long zB = (long)blockIdx.z * bBatch;
  const long zC = (long)blockIdx.z * cBatch;
  const int rowBase = blockIdx.y * 64;
  const int colBase = blockIdx.x * 512;

  auto STAGE = [&](int t) {
    ushortT* sA = lds[t & 1];
    ushortT* sB = sA + 64 * 64;
    const int k0 = t << 6;
    {
      int row = tid >> 3;                 // 0..63
      int ck  = ((tid & 7) ^ (row & 7)) << 3;
      long gofs = zA + (long)(rowBase + row) * lda + (k0 + ck);
      gload_lds16(A + gofs, sA + tid * 8);
    }
#pragma unroll
    for (int l = 0; l < 8; l++) {
      int idx = l * 512 + tid;            // 0..4095
      int row = idx >> 3;                 // 0..511
      int ck  = ((tid & 7) ^ (row & 7)) << 3;
      long gofs = zB + (long)(colBase + row) * ldb + (k0 + ck);
      gload_lds16(Bm + gofs, sB + idx * 8);
    }
  };

  auto LD = [&](const ushortT* s, int r, int c) -> bf16x8 {
    return *(const bf16x8*)&s[r * 64 + ((c ^ (r & 7)) << 3)];
  };

  floatx4 zero = {0.f, 0.f, 0.f, 0.f};
  floatx4 acc[4][4];
#pragma unroll
  for (int mi = 0; mi < 4; mi++)
#pragma unroll
    for (int ni = 0; ni < 4; ni++) acc[mi][ni] = zero;

  const int NT = Kdim >> 6;
  STAGE(0);
  STAGE(1);

  for (int t = 0; t < NT; t++) {
    if (t < NT - 1) asm volatile("s_waitcnt vmcnt(9)" ::: "memory");
    else            asm volatile("s_waitcnt vmcnt(0)" ::: "memory");
    __builtin_amdgcn_s_barrier();

    const ushortT* sA = lds[t & 1];
    const ushortT* sB = sA + 64 * 64;

    bf16x8 av[4][2], bv[4][2];
#pragma unroll
    for (int ni = 0; ni < 4; ni++)
#pragma unroll
      for (int ks = 0; ks < 2; ks++)
        bv[ni][ks] = LD(sB, wave * 64 + ni * 16 + l15, ks * 4 + quad);
#pragma unroll
    for (int mi = 0; mi < 4; mi++)
#pragma unroll
      for (int ks = 0; ks < 2; ks++)
        av[mi][ks] = LD(sA, mi * 16 + l15, ks * 4 + quad);

    __builtin_amdgcn_s_setprio(1);
#pragma unroll
    for (int mi = 0; mi < 4; mi++)
#pragma unroll
      for (int ni = 0; ni < 4; ni++)
#pragma unroll
        for (int ks = 0; ks < 2; ks++)
          acc[mi][ni] = __builtin_amdgcn_mfma_f32_16x16x32_bf16(av[mi][ks], bv[ni][ks], acc[mi][ni], 0, 0, 0);
    __builtin_amdgcn_s_setprio(0);

    __builtin_amdgcn_s_barrier();
    if (t + 2 < NT) STAGE(t + 2);
  }

  if (LNEPI) {
    float bov[4], lw[4], lb[4];
#pragma unroll
    for (int ni = 0; ni < 4; ni++) {
      int col = wave * 64 + ni * 16 + l15;
      bov[ni] = bias[col]; lw[ni] = lnw[col]; lb[ni] = lnb[col];
    }
    float* psum = (float*)&lds[0][0];
    float* pssq = psum + 8 * 64;
    __syncthreads();
#pragma unroll
    for (int mi = 0; mi < 4; mi++) {
#pragma unroll
      for (int r = 0; r < 4; r++) {
        int rowl = mi * 16 + quad * 4 + r;
        long grow = rowBase + rowl;
        float ps = 0.f, pq = 0.f;
#pragma unroll
        for (int ni = 0; ni < 4; ni++) {
          int col = wave * 64 + ni * 16 + l15;
          float val = acc[mi][ni][r] + bov[ni] + bf2f(hres[grow * 512 + col]);
          acc[mi][ni][r] = val;
          ps += val; pq += val * val;
        }
#pragma unroll
        for (int off = 1; off < 16; off <<= 1) { ps += __shfl_xor(ps, off); pq += __shfl_xor(pq, off); }
        if (l15 == 0) { psum[wave * 64 + rowl] = ps; pssq[wave * 64 + rowl] = pq; }
      }
    }
    __syncthreads();
#pragma unroll
    for (int mi = 0; mi < 4; mi++) {
#pragma unroll
      for (int r = 0; r < 4; r++) {
        int rowl = mi * 16 + quad * 4 + r;
        float S = 0.f, Q = 0.f;
#pragma unroll
        for (int w = 0; w < 8; w++) { S += psum[w * 64 + rowl]; Q += pssq[w * 64 + rowl]; }
        float mu = S * (1.0f / 512.0f);
        float rstd = rsqrtf(Q * (1.0f / 512.0f) - mu * mu + 1e-5f);
        long grow = rowBase + rowl;
#pragma unroll
        for (int ni = 0; ni < 4; ni++) {
          int col = wave * 64 + ni * 16 + l15;
          Cf[grow * 512 + col] = (acc[mi][ni][r] - mu) * rstd * lw[ni] + lb[ni];
        }
      }
    }
  } else {
#pragma unroll
    for (int mi = 0; mi < 4; mi++) {
#pragma unroll
      for (int ni = 0; ni < 4; ni++) {
        int gcol = colBase + wave * 64 + ni * 16 + l15;
        float bcol = (BIAS == 1) ? bias[gcol] : 0.0f;
#pragma unroll
        for (int r = 0; r < 4; r++) {
          int grow = rowBase + mi * 16 + quad * 4 + r;
          float val = acc[mi][ni][r] * scale + bcol + ((BIAS == 2) ? bias[grow] : 0.0f);
          long off = zC + (long)grow * ldc + gcol;
          if (WBF16) Cb[off] = f2bf(val);
          else       Cf[off] = val;
        }
      }
    }
  }
}

// ---------------- LN1 -> bf16 only ----------------
__global__ __launch_bounds__(128)
void k_ln(const float* __restrict__ src, const float* __restrict__ w, const float* __restrict__ b,
          ushortT* __restrict__ outb)
{
  __shared__ float s1[2], s2[2];
  long r = blockIdx.x;
  int tid = threadIdx.x;
  floatx4 v = *(const floatx4*)&src[r * 512 + tid * 4];
  float sum = v[0] + v[1] + v[2] + v[3];
  float ssq = v[0]*v[0] + v[1]*v[1] + v[2]*v[2] + v[3]*v[3];
#pragma unroll
  for (int off = 32; off; off >>= 1) { sum += __shfl_xor(sum, off); ssq += __shfl_xor(ssq, off); }
  if ((tid & 63) == 0) { s1[tid >> 6] = sum; s2[tid >> 6] = ssq; }
  __syncthreads();
  sum = s1[0] + s1[1]; ssq = s2[0] + s2[1];
  float mu = sum * (1.0f / 512.0f);
  float var = ssq * (1.0f / 512.0f) - mu * mu;
  float rstd = rsqrtf(var + 1e-5f);
  floatx4 wv = *(const floatx4*)&w[tid * 4];
  floatx4 bv = *(const floatx4*)&b[tid * 4];
  ushort4v ob;
#pragma unroll
  for (int j = 0; j < 4; j++) ob[j] = f2bf((v[j] - mu) * rstd * wv[j] + bv[j]);
  *(ushort4v*)&outb[r * 512 + tid * 4] = ob;
}

// ---------------- softmax: bf16 logits -> fp32 attn (d_out) + bf16 P in place ----------------
__global__ __launch_bounds__(256)
void k_softmax(ushortT* __restrict__ logits, float* __restrict__ attn)
{
  __shared__ float sred[4];
  long r = blockIdx.x;
  ushortT* lrow = logits + r * 2048;
  float* arow = attn + r * 2048;
  int tid = threadIdx.x;
  ushort8 uv = *(const ushort8*)&lrow[tid * 8];
  float v[8];
#pragma unroll
  for (int j = 0; j < 8; j++) v[j] = bf2f(uv[j]);
  float mx = v[0];
#pragma unroll
  for (int j = 1; j < 8; j++) mx = fmaxf(mx, v[j]);
#pragma unroll
  for (int off = 32; off; off >>= 1) mx = fmaxf(mx, __shfl_xor(mx, off));
  if ((tid & 63) == 0) sred[tid >> 6] = mx;
  __syncthreads();
  mx = fmaxf(fmaxf(sred[0], sred[1]), fmaxf(sred[2], sred[3]));
  __syncthreads();
  float sum = 0.f;
#pragma unroll
  for (int j = 0; j < 8; j++) { v[j] = __expf(v[j] - mx); sum += v[j]; }
#pragma unroll
  for (int off = 32; off; off >>= 1) sum += __shfl_xor(sum, off);
  if ((tid & 63) == 0) sred[tid >> 6] = sum;
  __syncthreads();
  sum = sred[0] + sred[1] + sred[2] + sred[3];
  float inv = 1.0f / sum;
  floatx4 o0, o1;
  ushort8 ob;
#pragma unroll
  for (int j = 0; j < 8; j++) {
    float p = v[j] * inv;
    if (j < 4) o0[j] = p; else o1[j - 4] = p;
    ob[j] = f2bf(p);
  }
  *(floatx4*)&arow[tid * 8] = o0;
  *(floatx4*)&arow[tid * 8 + 4] = o1;
  *(ushort8*)&lrow[tid * 8] = ob;
}

extern "C" void kernel_launch(void* const* d_in, const int* in_sizes, int n_in,
                              void* d_out, int out_size, void* d_ws, size_t ws_size,
                              hipStream_t stream)
{
  const float* x      = (const float*)d_in[0];
  const float* enc    = (const float*)d_in[1];
  const float* conv_w = (const float*)d_in[2];
  const float* conv_b = (const float*)d_in[3];
  const float* ln1_w  = (const float*)d_in[4];
  const float* ln1_b  = (const float*)d_in[5];
  const float* Wq     = (const float*)d_in[6];
  const float* bq     = (const float*)d_in[7];
  const float* Wk     = (const float*)d_in[8];
  const float* bk     = (const float*)d_in[9];
  const float* Wv     = (const float*)d_in[10];
  const float* bv     = (const float*)d_in[11];
  const float* Wo     = (const float*)d_in[12];
  const float* bo     = (const float*)d_in[13];
  const float* ln2_w  = (const float*)d_in[14];
  const float* ln2_b  = (const float*)d_in[15];

  const long BT = 16384, Dd = 512, S = 2048, TT = 2048;
  float* out  = (float*)d_out;
  float* attn = out + BT * Dd;

  char* p = (char*)d_ws;
  auto alloc = [&](size_t bytes) { char* r = p; p += (bytes + 255) & ~255UL; return r; };
  float*   hglu  = (float*)alloc(BT * Dd * 4);
  ushortT* xpad  = (ushortT*)alloc(8L * 2050 * 512 * 2);
  ushortT* encbf = (ushortT*)alloc(BT * Dd * 2);
  ushortT* hbf   = (ushortT*)alloc(BT * Dd * 2);
  ushortT* qbf   = (ushortT*)alloc(BT * Dd * 2);
  ushortT* kbf   = (ushortT*)alloc(BT * Dd * 2);
  ushortT* vT    = (ushortT*)alloc(Dd * BT * 2);    // [512][16384]
  ushortT* ctxbf = (ushortT*)alloc(BT * Dd * 2);
  ushortT* sl    = (ushortT*)alloc(BT * S * 2);     // logits, then P (bf16)
  ushortT* Wcbf  = (ushortT*)alloc(1024L * 1536 * 2);
  ushortT* wall  = (ushortT*)alloc(4L * 262144 * 2);
  ushortT* Wqbf = wall, *Wkbf = wall + 262144, *Wvbf = wall + 2 * 262144, *Wobf = wall + 3 * 262144;

  // conversions
  k_xpad<<<8 * 2050, 128, 0, stream>>>(x, xpad);
  k_f32_to_bf16v<<<(BT * Dd / 4 + 255) / 256, 256, 0, stream>>>(enc, encbf, BT * Dd / 4);
  k_convw<<<(1024 * 1536 + 255) / 256, 256, 0, stream>>>(conv_w, Wcbf);
  k_w4<<<1024, 256, 0, stream>>>(Wq, Wk, Wv, Wo, wall);

  // conv GEMM + fused GLU + residual -> hglu fp32   (M=16384, N=1024, K=1536)
  k_gemm256<1, 1, 0, 0, 0, 0><<<dim3(64, 4, 1), 512, 0, stream>>>(
      xpad, nullptr, 0, 0, Wcbf, nullptr, 1536, 0,
      conv_b, nullptr, x, hglu, nullptr, nullptr, 0, 512, 1536, 1.0f);
  // LN1 -> hbf bf16
  k_ln<<<16384, 128, 0, stream>>>(hglu, ln1_w, ln1_b, hbf);

  // q = h @ Wq^T + bq  (z=0)  ||  k = enc @ Wk^T + bk  (z=1)
  k_gemm256<0, 0, 1, 1, 1, 0><<<dim3(64, 2, 2), 512, 0, stream>>>(
      hbf, encbf, 512, 0, Wqbf, Wkbf, 512, 0,
      bq, bk, nullptr, nullptr, qbf, kbf, 0, 512, 512, 1.0f);

  // vT = Wv @ enc^T + bv (row bias) -> [512][16384]
  k_gemm64<2, 1, 0><<<dim3(32, 8, 1), 512, 0, stream>>>(
      Wvbf, 512, 0, encbf, 512, 0,
      bv, nullptr, nullptr, nullptr,
      nullptr, vT, 0, 16384, 512, 1.0f);

  // scores -> bf16 logits in sl  (per batch 2048x2048, K=512)
  k_gemm256<0, 0, 0, 1, 0, 0><<<dim3(8, 8, 8), 512, 0, stream>>>(
      qbf, nullptr, 512, TT * Dd, kbf, nullptr, 512, S * Dd,
      nullptr, nullptr, nullptr, nullptr, sl, nullptr,
      TT * S, 2048, 512, 0.04419417382415922f);
  // softmax: sl -> attn fp32 (d_out) + P bf16 in place
  k_softmax<<<16384, 256, 0, stream>>>(sl, attn);

  // ctx = P @ v : 128x256 tiles, XCD-swizzled (batch == XCD), full-GPU 256 blocks
  k_ctx128<<<256, 512, 0, stream>>>(sl, vT, ctxbf);

  // fused out-proj + residual + LN2 -> out  (M=16384: 256 blocks, BN=512 full row)
  k_gemm64<0, 0, 1><<<dim3(1, 256, 1), 512, 0, stream>>>(
      ctxbf, 512, 0, Wobf, 512, 0,
      bo, hbf, ln2_w, ln2_b,
      out, nullptr, 0, 512, 512, 1.0f);
}